// Round 5
// baseline (214.159 us; speedup 1.0000x reference)
//
#include <hip/hip_runtime.h>

#define N_FEATURES 4096
#define N_GROUPS   1024
#define BATCH      8192
#define NV4        (N_FEATURES / 4)   // 1024 float4 per row

// Kernel 1: coeff[f] = sum_{i: flat_idx[i]==f} w_flat[i]*diag_w[seg[i]]*dense_W[seg[i]]
// Single block; up to 5 entries/thread with independent front-loaded gathers
// (2 dependent hops total), LDS accumulate, write 4096 floats to d_ws.
__global__ __launch_bounds__(1024) void build_coeff_kernel(
    const int* __restrict__ flat_idx,
    const int* __restrict__ seg_ids,
    const float* __restrict__ w_flat,
    const float* __restrict__ diag_w,
    const float* __restrict__ dense_W,
    float* __restrict__ coeff,
    int total)
{
    __shared__ float s_coeff[N_FEATURES];
    for (int i = threadIdx.x; i < N_FEATURES; i += blockDim.x) s_coeff[i] = 0.0f;
    __syncthreads();

    // front-load independent gathers: idx/seg/w for all my entries
    int   my_i[5];  int my_idx[5];  int my_g[5];  float my_w[5];
    int   cnt = 0;
    for (int i = threadIdx.x; i < total; i += blockDim.x) {
        my_i[cnt] = i;
        my_idx[cnt] = flat_idx[i];
        my_g[cnt]   = seg_ids[i];
        my_w[cnt]   = w_flat[i];
        ++cnt;
    }
    float my_c[5];
    for (int k = 0; k < cnt; ++k)
        my_c[k] = my_w[k] * diag_w[my_g[k]] * dense_W[my_g[k]];
    for (int k = 0; k < cnt; ++k)
        atomicAdd(&s_coeff[my_idx[k]], my_c[k]);

    __syncthreads();
    for (int i = threadIdx.x; i < N_FEATURES; i += blockDim.x) coeff[i] = s_coeff[i];
}

// Kernel 2: out[b] = dot(x[b,:], coeff).  One wave per row, no LDS/barrier.
// PHASE ROTATION: rows are 16 KB apart, so lockstep waves all present the
// same low address bits -> HBM channel / L2 set camping (the suspected
// structure-insensitive ~2 TB/s cap of R0/R1/R4). Rotating each row's chunk
// order by (row & 15) makes the instantaneous address set span the full
// 16 KB period -> all channels busy.
__global__ __launch_bounds__(256, 4) void gemv_kernel(
    const float* __restrict__ x,
    const float* __restrict__ coeff,
    float* __restrict__ out)
{
    const int wid   = threadIdx.x >> 6;
    const int lane  = threadIdx.x & 63;
    const int row   = (blockIdx.x << 2) + wid;
    const int phase = row & 15;          // consecutive rows -> consecutive phases

    const float4* __restrict__ xr = (const float4*)(x + (size_t)row * N_FEATURES);
    const float4* __restrict__ c4 = (const float4*)coeff;

    // 16 outstanding dwordx4 per lane, rotated start chunk per row
    float4 xv[16];
#pragma unroll
    for (int k = 0; k < 16; ++k)
        xv[k] = xr[((((k + phase) & 15)) << 6) + lane];

    float acc = 0.0f;
#pragma unroll
    for (int k = 0; k < 16; ++k) {
        float4 cv = c4[((((k + phase) & 15)) << 6) + lane];  // L1-resident 16 KB
        acc += xv[k].x * cv.x + xv[k].y * cv.y + xv[k].z * cv.z + xv[k].w * cv.w;
    }

    // 64-lane shuffle reduction
#pragma unroll
    for (int off = 32; off > 0; off >>= 1)
        acc += __shfl_down(acc, off, 64);

    if (lane == 0)
        out[row] = acc;
}

extern "C" void kernel_launch(void* const* d_in, const int* in_sizes, int n_in,
                              void* d_out, int out_size, void* d_ws, size_t ws_size,
                              hipStream_t stream) {
    const float* x        = (const float*)d_in[0];  // [BATCH, N_FEATURES]
    const int*   flat_idx = (const int*)d_in[1];    // [total]
    const int*   seg_ids  = (const int*)d_in[2];    // [total]
    const float* w_flat   = (const float*)d_in[3];  // [total]
    const float* diag_w   = (const float*)d_in[4];  // [N_GROUPS]
    const float* dense_W  = (const float*)d_in[5];  // [N_GROUPS]
    float* out = (float*)d_out;                     // [BATCH] (shape [BATCH,1])
    const int total = in_sizes[1];

    float* coeff = (float*)d_ws;  // N_FEATURES floats of scratch

    build_coeff_kernel<<<1, 1024, 0, stream>>>(flat_idx, seg_ids, w_flat,
                                               diag_w, dense_W, coeff, total);
    gemv_kernel<<<BATCH / 4, 256, 0, stream>>>(x, coeff, out);
}

// Round 6
// 210.855 us; speedup vs baseline: 1.0157x; 1.0157x over previous
//
#include <hip/hip_runtime.h>

#define N_FEATURES 4096
#define N_GROUPS   1024
#define BATCH      8192
#define NV4        (N_FEATURES / 4)   // 1024 float4 per row

// Kernel 1: coeff[f] = sum_{i: flat_idx[i]==f} w_flat[i]*diag_w[seg[i]]*dense_W[seg[i]]
// Single block, 1024 threads; front-loaded independent gathers, LDS accumulate.
__global__ __launch_bounds__(1024) void build_coeff_kernel(
    const int* __restrict__ flat_idx,
    const int* __restrict__ seg_ids,
    const float* __restrict__ w_flat,
    const float* __restrict__ diag_w,
    const float* __restrict__ dense_W,
    float* __restrict__ coeff,
    int total)
{
    __shared__ float s_coeff[N_FEATURES];
    for (int i = threadIdx.x; i < N_FEATURES; i += blockDim.x) s_coeff[i] = 0.0f;
    __syncthreads();

    int my_idx[5]; int my_g[5]; float my_w[5];
    int cnt = 0;
    for (int i = threadIdx.x; i < total; i += blockDim.x) {
        my_idx[cnt] = flat_idx[i];
        my_g[cnt]   = seg_ids[i];
        my_w[cnt]   = w_flat[i];
        ++cnt;
    }
    for (int k = 0; k < cnt; ++k) {
        float c = my_w[k] * diag_w[my_g[k]] * dense_W[my_g[k]];
        atomicAdd(&s_coeff[my_idx[k]], c);
    }
    __syncthreads();
    for (int i = threadIdx.x; i < N_FEATURES; i += blockDim.x) coeff[i] = s_coeff[i];
}

// Kernel 2: out[b] = dot(x[b,:], coeff).
// 512 blocks x 256 threads = 2048 waves; each wave owns 4 consecutive rows.
// coeff is loaded into registers ONCE per wave (cv[16] = 64 VGPRs), then a
// 2-deep software pipeline across rows keeps 16 KB of x loads continuously
// in flight per wave: issue row r+1's 16 dwordx4 into the spare buffer,
// then reduce row r (reduction touches only acc/cv -> loads stay outstanding).
// No LDS, no barrier. __launch_bounds__(256,2): ~210 VGPR fits 2 waves/EU.
__global__ __launch_bounds__(256, 2) void gemv_kernel(
    const float* __restrict__ x,
    const float* __restrict__ coeff,
    float* __restrict__ out)
{
    const int wid  = threadIdx.x >> 6;
    const int lane = threadIdx.x & 63;
    const int wave = (blockIdx.x << 2) + wid;   // 0..2047
    const int row0 = wave << 2;                 // 4 rows per wave

    const float4* __restrict__ c4 = (const float4*)coeff;

    // coeff resident in registers
    float4 cv[16];
#pragma unroll
    for (int k = 0; k < 16; ++k)
        cv[k] = c4[(k << 6) + lane];

    // prologue: row0 -> xa
    const float4* __restrict__ xr = (const float4*)(x + (size_t)row0 * N_FEATURES);
    float4 xa[16], xb[16];
#pragma unroll
    for (int k = 0; k < 16; ++k)
        xa[k] = xr[(k << 6) + lane];

#pragma unroll
    for (int r = 0; r < 4; ++r) {
        // prefetch next row into the spare buffer (independent of reduction)
        if (r < 3) {
            const float4* __restrict__ xn =
                (const float4*)(x + (size_t)(row0 + r + 1) * N_FEATURES);
            if (r & 1) {
#pragma unroll
                for (int k = 0; k < 16; ++k) xa[k] = xn[(k << 6) + lane];
            } else {
#pragma unroll
                for (int k = 0; k < 16; ++k) xb[k] = xn[(k << 6) + lane];
            }
        }

        // consume current buffer (even r -> xa, odd r -> xb)
        float acc = 0.0f;
        if (r & 1) {
#pragma unroll
            for (int k = 0; k < 16; ++k)
                acc += xb[k].x * cv[k].x + xb[k].y * cv[k].y +
                       xb[k].z * cv[k].z + xb[k].w * cv[k].w;
        } else {
#pragma unroll
            for (int k = 0; k < 16; ++k)
                acc += xa[k].x * cv[k].x + xa[k].y * cv[k].y +
                       xa[k].z * cv[k].z + xa[k].w * cv[k].w;
        }

        // 64-lane shuffle reduction (does not touch load buffers)
#pragma unroll
        for (int off = 32; off > 0; off >>= 1)
            acc += __shfl_down(acc, off, 64);

        if (lane == 0)
            out[row0 + r] = acc;
    }
}

extern "C" void kernel_launch(void* const* d_in, const int* in_sizes, int n_in,
                              void* d_out, int out_size, void* d_ws, size_t ws_size,
                              hipStream_t stream) {
    const float* x        = (const float*)d_in[0];  // [BATCH, N_FEATURES]
    const int*   flat_idx = (const int*)d_in[1];    // [total]
    const int*   seg_ids  = (const int*)d_in[2];    // [total]
    const float* w_flat   = (const float*)d_in[3];  // [total]
    const float* diag_w   = (const float*)d_in[4];  // [N_GROUPS]
    const float* dense_W  = (const float*)d_in[5];  // [N_GROUPS]
    float* out = (float*)d_out;                     // [BATCH] (shape [BATCH,1])
    const int total = in_sizes[1];

    float* coeff = (float*)d_ws;  // N_FEATURES floats of scratch

    build_coeff_kernel<<<1, 1024, 0, stream>>>(flat_idx, seg_ids, w_flat,
                                               diag_w, dense_W, coeff, total);
    gemv_kernel<<<BATCH / 16, 256, 0, stream>>>(x, coeff, out);
}